// Round 14
// baseline (3292.487 us; speedup 1.0000x reference)
//
#include <hip/hip_runtime.h>
#include <math.h>

// Problem constants (from reference)
#define NQ 32768   // query points (pos1)
#define MC 8192    // source points (pos2)
#define CC 128     // channels
#define EPS_BN 1e-5f
#define EPS_D  1e-8

#define DBL_BIG 1e300
#define IDX_BIG 0x7fffffff

#define KMASK 0xFFFFE000u   // keep sign+exp+10 mantissa bits of d
#define IMASK 0x1FFFu       // 13-bit index (M=8192)
#define GEMM_B (NQ / 64)    // 512
#define NGRP 8              // stats atomic groups (R11-proven)

// Grid-KNN config
#define GG   64                 // grid cells per axis
#define GT   (GG * GG * GG)     // 262144 cells
#define BMIN (-6.0f)
#define HCELL 0.1875f           // 12 / 64
#define INVH  5.3333335f
#define RCAP  24                // ring cap (physically never reached)

typedef __attribute__((ext_vector_type(8))) short bf16x8;   // 8 bf16 (4 VGPRs)
typedef __attribute__((ext_vector_type(4))) float floatx4;  // MFMA accumulator
typedef unsigned short ushort_t;

__device__ __forceinline__ unsigned umin_(unsigned a, unsigned b) { return a < b ? a : b; }
__device__ __forceinline__ unsigned umax_(unsigned a, unsigned b) { return a > b ? a : b; }

// RNE fp32 -> bf16 pair packed in u32 (lo = a, hi = b)
__device__ __forceinline__ unsigned bf16pair(float a, float b) {
    unsigned ua = __float_as_uint(a); ua = (ua + 0x7FFFu + ((ua >> 16) & 1u)) >> 16;
    unsigned ub = __float_as_uint(b); ub = (ub + 0x7FFFu + ((ub >> 16) & 1u)) >> 16;
    return ua | (ub << 16);
}
__device__ __forceinline__ ushort_t bf16one(float a) {
    unsigned ua = __float_as_uint(a);
    return (ushort_t)((ua + 0x7FFFu + ((ua >> 16) & 1u)) >> 16);
}
__device__ __forceinline__ float bflo(unsigned u) { return __uint_as_float(u << 16); }
__device__ __forceinline__ float bfhi(unsigned u) { return __uint_as_float(u & 0xFFFF0000u); }

__device__ __forceinline__ int cellcoord(float v) {
    int c = (int)floorf((v - BMIN) * INVH);
    return c < 0 ? 0 : (c > GG - 1 ? GG - 1 : c);
}

// ---------------------------------------------------------------------------
// prep: blocks [0,32): histogram pos2 into cnt[] + record cellOf[i].
//       blocks [32,40): convert W0/W1/W2 fp32 -> bf16 (RNE).
// cnt/stats zeroed by a preceding hipMemsetAsync.
// ---------------------------------------------------------------------------
__global__ __launch_bounds__(256) void prep_kernel(const float* __restrict__ pos2,
                                                   int* __restrict__ cnt,
                                                   int* __restrict__ cellOf,
                                                   const float* __restrict__ W0,
                                                   const float* __restrict__ W1,
                                                   const float* __restrict__ W2,
                                                   ushort_t* __restrict__ Wbf) {
    if (blockIdx.x >= 32) {
        const int pb = blockIdx.x - 32;
        const float* Ws[3] = {W0, W1, W2};
#pragma unroll
        for (int l = 0; l < 3; ++l) {
            unsigned* dst = (unsigned*)(Wbf + (size_t)l * CC * CC);
#pragma unroll
            for (int k = 0; k < 2; ++k) {
                const int f = (pb * 256 + threadIdx.x) * 2 + k;   // float4 idx < 4096
                const float4 v = ((const float4*)Ws[l])[f];
                dst[f * 2 + 0] = bf16pair(v.x, v.y);
                dst[f * 2 + 1] = bf16pair(v.z, v.w);
            }
        }
        return;
    }
    const int i = blockIdx.x * 256 + threadIdx.x;   // 0..8191
    const float x = pos2[i * 3 + 0];
    const float y = pos2[i * 3 + 1];
    const float z = pos2[i * 3 + 2];
    const int c = (cellcoord(z) << 12) | (cellcoord(y) << 6) | cellcoord(x);
    cellOf[i] = c;
    atomicAdd(&cnt[c], 1);
}

// ---------------------------------------------------------------------------
// scanA: 256 blocks x 1024; block b scans cnt[b*1024 .. +1024) -> local
// exclusive prefix into off[]; blockSum[b] = block total.
// ---------------------------------------------------------------------------
__global__ __launch_bounds__(1024) void scanA(const int* __restrict__ cnt,
                                              int* __restrict__ off,
                                              int* __restrict__ blockSum) {
    __shared__ int lds[1024];
    const int t = threadIdx.x;
    const int cell = blockIdx.x * 1024 + t;
    const int my = cnt[cell];
    lds[t] = my;
    __syncthreads();
#pragma unroll
    for (int o = 1; o < 1024; o <<= 1) {
        int v = (t >= o) ? lds[t - o] : 0;
        __syncthreads();
        lds[t] += v;
        __syncthreads();
    }
    off[cell] = lds[t] - my;            // exclusive within block
    if (t == 1023) blockSum[blockIdx.x] = lds[1023];
}

// ---------------------------------------------------------------------------
// scanC: 256 blocks x 1024; each block redundantly scans blockSum[256] ->
// its base, adds to off[], copies to cursor[]. Block 255/thread 1023 writes
// the final off[GT].
// ---------------------------------------------------------------------------
__global__ __launch_bounds__(1024) void scanC(const int* __restrict__ blockSum,
                                              int* __restrict__ off,
                                              int* __restrict__ cursor) {
    __shared__ int base[257];
    if (threadIdx.x == 0) {
        int run = 0;
        for (int b = 0; b < 256; ++b) { base[b] = run; run += blockSum[b]; }
        base[256] = run;   // total = 8192
    }
    __syncthreads();
    const int cell = blockIdx.x * 1024 + threadIdx.x;
    const int v = off[cell] + base[blockIdx.x];
    off[cell] = v;
    cursor[cell] = v;
    if (blockIdx.x == 255 && threadIdx.x == 1023) off[GT] = base[256];
}

// ---------------------------------------------------------------------------
// scatter: place each point into its cell bucket: pts[pos]=(x,y,z,idx-bits).
// ---------------------------------------------------------------------------
__global__ __launch_bounds__(256) void scatter_kernel(const float* __restrict__ pos2,
                                                      const int* __restrict__ cellOf,
                                                      int* __restrict__ cursor,
                                                      float4* __restrict__ pts) {
    const int i = blockIdx.x * 256 + threadIdx.x;   // 0..8191
    const int c = cellOf[i];
    const int pos = atomicAdd(&cursor[c], 1);
    pts[pos] = make_float4(pos2[i * 3 + 0], pos2[i * 3 + 1], pos2[i * 3 + 2],
                           __int_as_float(i));
}

// ---------------------------------------------------------------------------
// Grid KNN query: 512 blocks x 256 thr; 4 threads per query (cell-granular
// partition). Ring expansion r=1..RCAP; after completing Chebyshev ring r,
// unseen points have d >= (r*HCELL)^2 -> stop when quantized d3*1.002 <= it.
// Per-lane top-4 as sortable keys (bits(d)&KMASK)|idx; per-ring block merge
// (1 thread/query over the 16 published keys). Final: top-4-of-16 -> exact
// fp64 re-rank (index tie-break, matches float64 numpy ordering) -> idx3/w3.
// ---------------------------------------------------------------------------
__global__ __launch_bounds__(256) void knn_query(const float* __restrict__ pos1,
                                                 const float4* __restrict__ pts,
                                                 const int* __restrict__ off,
                                                 const float* __restrict__ pos2,
                                                 int* __restrict__ idx3,
                                                 float* __restrict__ w3) {
    __shared__ unsigned sk[64][16];
    __shared__ int qd[64];
    __shared__ int ndone;

    const int t = threadIdx.x;
    const int ql = t >> 2;          // query-in-block 0..63
    const int p  = t & 3;           // partition 0..3
    const int q  = blockIdx.x * 64 + ql;

    const float qx = pos1[q * 3 + 0];
    const float qy = pos1[q * 3 + 1];
    const float qz = pos1[q * 3 + 2];
    const int cx = cellcoord(qx), cy = cellcoord(qy), cz = cellcoord(qz);

    unsigned k0 = 0xFFFFFFFFu, k1 = 0xFFFFFFFFu, k2 = 0xFFFFFFFFu, k3 = 0xFFFFFFFFu;

    if (t < 64) qd[t] = 0;
    if (t == 0) ndone = 0;
    __syncthreads();

    for (int r = 1; r <= RCAP; ++r) {
        if (!qd[ql]) {
            const int zlo = max(cz - r, 0), zhi = min(cz + r, GG - 1);
            const int ylo = max(cy - r, 0), yhi = min(cy + r, GG - 1);
            const int xlo = max(cx - r, 0), xhi = min(cx + r, GG - 1);
            int cellCnt = 0;
            for (int z = zlo; z <= zhi; ++z) {
                const int az = abs(z - cz);
                for (int y = ylo; y <= yhi; ++y) {
                    const int ay = abs(y - cy);
                    const int am = az > ay ? az : ay;
                    for (int x = xlo; x <= xhi; ++x) {
                        if (r > 1) {
                            const int ax = abs(x - cx);
                            if ((am > ax ? am : ax) != r) continue;   // shell only
                        }
                        if (((cellCnt++) & 3) != p) continue;         // partition
                        const int c = (z << 12) | (y << 6) | x;
                        const int s = off[c], e = off[c + 1];
                        for (int i = s; i < e; ++i) {
                            const float4 pt = pts[i];
                            const float dx = qx - pt.x, dy = qy - pt.y, dz = qz - pt.z;
                            const float d = fmaf(dx, dx, fmaf(dy, dy, dz * dz));
                            unsigned e_ = (__float_as_uint(d) & KMASK) | __float_as_uint(pt.w);
                            if (e_ < k3) {
                                unsigned tt;
                                tt = umin_(k0, e_); e_ = umax_(k0, e_); k0 = tt;
                                tt = umin_(k1, e_); e_ = umax_(k1, e_); k1 = tt;
                                tt = umin_(k2, e_); e_ = umax_(k2, e_); k2 = tt;
                                k3 = umin_(k3, e_);
                            }
                        }
                    }
                }
            }
            sk[ql][p * 4 + 0] = k0;
            sk[ql][p * 4 + 1] = k1;
            sk[ql][p * 4 + 2] = k2;
            sk[ql][p * 4 + 3] = k3;
        }
        __syncthreads();
        if (t < 64 && !qd[t]) {
            // 3rd smallest of the 16 published keys
            unsigned a = 0xFFFFFFFFu, b = 0xFFFFFFFFu, c3 = 0xFFFFFFFFu;
#pragma unroll
            for (int s = 0; s < 16; ++s) {
                const unsigned k = sk[t][s];
                if (k < c3) {
                    if (k < b) {
                        if (k < a) { c3 = b; b = a; a = k; }
                        else       { c3 = b; b = k; }
                    } else c3 = k;
                }
            }
            const float d3q = __uint_as_float(c3 & KMASK);   // NaN if <3 found
            const float rb = (float)r * HCELL;
            if (d3q * 1.002f <= rb * rb) {
                qd[t] = 1;
                atomicAdd(&ndone, 1);
            }
        }
        __syncthreads();
        if (ndone == 64) break;
    }

    // final: top-4 of 16 -> fp64 exact re-rank -> idx3 / w3
    if (t < 64) {
        unsigned a = 0xFFFFFFFFu, b = 0xFFFFFFFFu, c3 = 0xFFFFFFFFu, d4 = 0xFFFFFFFFu;
#pragma unroll
        for (int s = 0; s < 16; ++s) {
            unsigned k = sk[t][s];
            if (k < d4) {
                unsigned tt;
                tt = umin_(a, k); k = umax_(a, k); a = tt;
                tt = umin_(b, k); k = umax_(b, k); b = tt;
                tt = umin_(c3, k); k = umax_(c3, k); c3 = tt;
                d4 = umin_(d4, k);
            }
        }
        const int qg = blockIdx.x * 64 + t;
        const double dqx = (double)pos1[qg * 3 + 0];
        const double dqy = (double)pos1[qg * 3 + 1];
        const double dqz = (double)pos1[qg * 3 + 2];
        double b0 = DBL_BIG, b1 = DBL_BIG, b2 = DBL_BIG;
        int    j0 = IDX_BIG, j1 = IDX_BIG, j2 = IDX_BIG;
        const unsigned cand[4] = {a, b, c3, d4};
#pragma unroll
        for (int s = 0; s < 4; ++s) {
            if (cand[s] == 0xFFFFFFFFu) continue;
            const int id = (int)(cand[s] & IMASK);
            const double x = (double)pos2[id * 3 + 0];
            const double y = (double)pos2[id * 3 + 1];
            const double z = (double)pos2[id * 3 + 2];
            const double ax = dqx - x, ay = dqy - y, az = dqz - z;
            const double d = ax * ax + ay * ay + az * az;
            const bool l2 = (d < b2) || (d == b2 && id < j2);
            if (l2) {
                const bool l1 = (d < b1) || (d == b1 && id < j1);
                const bool l0 = (d < b0) || (d == b0 && id < j0);
                b2 = l1 ? b1 : d;              j2 = l1 ? j1 : id;
                b1 = l1 ? (l0 ? b0 : d) : b1;  j1 = l1 ? (l0 ? j0 : id) : j1;
                b0 = l0 ? d : b0;              j0 = l0 ? id : j0;
            }
        }
        const double r0 = 1.0 / (b0 + EPS_D);
        const double r1 = 1.0 / (b1 + EPS_D);
        const double r2 = 1.0 / (b2 + EPS_D);
        const double inv = 1.0 / (r0 + r1 + r2);
        idx3[qg * 3 + 0] = j0; idx3[qg * 3 + 1] = j1; idx3[qg * 3 + 2] = j2;
        w3[qg * 3 + 0] = (float)(r0 * inv);
        w3[qg * 3 + 1] = (float)(r1 * inv);
        w3[qg * 3 + 2] = (float)(r2 * inv);
    }
}

// ---------------------------------------------------------------------------
// bf16-MFMA fused layer GEMM (R11-proven structure, NGRP=8).
//   MODE 0: Xin = interp(feat2(fp32), idx3, w3)   (idx3/w3 staged in LDS)
//   MODE 1: stats[8][256] -> BN scale/shift in LDS, Xin = relu(Xbf16*sc+sh)
// Y out: bf16. Epilogue stats -> 8-group atomicAdd. grid=512, block=256.
// ---------------------------------------------------------------------------
template <int MODE>
__global__ __launch_bounds__(256) void gemm_mfma(const void* __restrict__ Xsrc_,
                                                 const int* __restrict__ idx3,
                                                 const float* __restrict__ w3,
                                                 const float* __restrict__ statsIn,
                                                 const float* __restrict__ gIn,
                                                 const float* __restrict__ beIn,
                                                 const ushort_t* __restrict__ Wb,
                                                 const float* __restrict__ bias,
                                                 ushort_t* __restrict__ Y,
                                                 float* __restrict__ statsOut) {
    __shared__ __align__(16) short xa[64][136];    // X tile bf16
    __shared__ __align__(16) short wb[128][136];   // W tile bf16
    __shared__ float blk_s[CC], blk_q[CC];
    __shared__ float sc_l[CC], sh_l[CC];

    const int row0 = blockIdx.x * 64;

    if constexpr (MODE == 0) {
        __shared__ int   lidx[192];
        __shared__ float lwv[192];
        const float* feat2 = (const float*)Xsrc_;
        if (threadIdx.x < 192) {
            lidx[threadIdx.x] = idx3[row0 * 3 + threadIdx.x];
            lwv[threadIdx.x]  = w3[row0 * 3 + threadIdx.x];
        }
        if (threadIdx.x < CC) { blk_s[threadIdx.x] = 0.f; blk_q[threadIdx.x] = 0.f; }
        __syncthreads();
#pragma unroll
        for (int e = threadIdx.x; e < 64 * 32; e += 256) {
            const int r = e >> 5, c4 = e & 31;
            const int i0 = lidx[r * 3 + 0], i1 = lidx[r * 3 + 1], i2 = lidx[r * 3 + 2];
            const float w0 = lwv[r * 3 + 0], w1 = lwv[r * 3 + 1], w2 = lwv[r * 3 + 2];
            const float4 f0 = *(const float4*)&feat2[(size_t)i0 * CC + c4 * 4];
            const float4 f1 = *(const float4*)&feat2[(size_t)i1 * CC + c4 * 4];
            const float4 f2 = *(const float4*)&feat2[(size_t)i2 * CC + c4 * 4];
            float4 v;
            v.x = w0 * f0.x + w1 * f1.x + w2 * f2.x;
            v.y = w0 * f0.y + w1 * f1.y + w2 * f2.y;
            v.z = w0 * f0.z + w1 * f1.z + w2 * f2.z;
            v.w = w0 * f0.w + w1 * f1.w + w2 * f2.w;
            unsigned* dst = (unsigned*)&xa[r][0];
            dst[c4 * 2 + 0] = bf16pair(v.x, v.y);
            dst[c4 * 2 + 1] = bf16pair(v.z, v.w);
        }
    } else {
        const ushort_t* Xbf = (const ushort_t*)Xsrc_;
        if (threadIdx.x < CC) {
            const int c = threadIdx.x;
            float s = 0.f, qv = 0.f;
#pragma unroll
            for (int gr = 0; gr < NGRP; ++gr) {
                s += statsIn[gr * 256 + c];
                qv += statsIn[gr * 256 + CC + c];
            }
            const float m = s * (1.f / (float)NQ);
            const float v = fmaf(-m, m, qv * (1.f / (float)NQ));
            const float rstd = rsqrtf(v + EPS_BN);
            const float scl = gIn[c] * rstd;
            sc_l[c] = scl;
            sh_l[c] = fmaf(-m, scl, beIn[c]);
            blk_s[c] = 0.f; blk_q[c] = 0.f;
        }
        __syncthreads();
#pragma unroll
        for (int e = threadIdx.x; e < 64 * 16; e += 256) {
            const int r = e >> 4, c8 = e & 15;
            const uint4 u = *(const uint4*)&Xbf[(size_t)(row0 + r) * CC + c8 * 8];
            const float4 s0 = *(const float4*)&sc_l[c8 * 8];
            const float4 s1 = *(const float4*)&sc_l[c8 * 8 + 4];
            const float4 h0 = *(const float4*)&sh_l[c8 * 8];
            const float4 h1 = *(const float4*)&sh_l[c8 * 8 + 4];
            const float v0 = fmaxf(fmaf(bflo(u.x), s0.x, h0.x), 0.f);
            const float v1 = fmaxf(fmaf(bfhi(u.x), s0.y, h0.y), 0.f);
            const float v2 = fmaxf(fmaf(bflo(u.y), s0.z, h0.z), 0.f);
            const float v3 = fmaxf(fmaf(bfhi(u.y), s0.w, h0.w), 0.f);
            const float v4 = fmaxf(fmaf(bflo(u.z), s1.x, h1.x), 0.f);
            const float v5 = fmaxf(fmaf(bfhi(u.z), s1.y, h1.y), 0.f);
            const float v6 = fmaxf(fmaf(bflo(u.w), s1.z, h1.z), 0.f);
            const float v7 = fmaxf(fmaf(bfhi(u.w), s1.w, h1.w), 0.f);
            uint4 o;
            o.x = bf16pair(v0, v1); o.y = bf16pair(v2, v3);
            o.z = bf16pair(v4, v5); o.w = bf16pair(v6, v7);
            *(uint4*)&xa[r][c8 * 8] = o;
        }
    }
#pragma unroll
    for (int e = threadIdx.x; e < 128 * 16; e += 256) {
        const int co = e >> 4, seg = e & 15;
        *(float4*)&wb[co][seg * 8] = *(const float4*)&Wb[(size_t)co * CC + seg * 8];
    }
    __syncthreads();

    const int lane = threadIdx.x & 63;
    const int wv = threadIdx.x >> 6;
    const int nn = lane & 15;
    const int quad = lane >> 4;

    floatx4 acc[8] = {};

    const short* arow = &xa[wv * 16 + nn][0];
#pragma unroll
    for (int ks = 0; ks < 4; ++ks) {
        const bf16x8 a = *(const bf16x8*)(arow + ks * 32 + quad * 8);
#pragma unroll
        for (int ct = 0; ct < 8; ++ct) {
            const bf16x8 b = *(const bf16x8*)(&wb[ct * 16 + nn][0] + ks * 32 + quad * 8);
            acc[ct] = __builtin_amdgcn_mfma_f32_16x16x32_bf16(a, b, acc[ct], 0, 0, 0);
        }
    }

#pragma unroll
    for (int ct = 0; ct < 8; ++ct) {
        const float bv = bias[ct * 16 + nn];
        float s = 0.f, qv = 0.f;
#pragma unroll
        for (int r = 0; r < 4; ++r) {
            acc[ct][r] += bv;
            s += acc[ct][r];
            qv = fmaf(acc[ct][r], acc[ct][r], qv);
        }
#pragma unroll
        for (int r = 0; r < 4; ++r)
            Y[(size_t)(row0 + wv * 16 + quad * 4 + r) * CC + ct * 16 + nn] = bf16one(acc[ct][r]);
        s += __shfl_xor(s, 16, 64); s += __shfl_xor(s, 32, 64);
        qv += __shfl_xor(qv, 16, 64); qv += __shfl_xor(qv, 32, 64);
        if (quad == 0) {
            atomicAdd(&blk_s[ct * 16 + nn], s);
            atomicAdd(&blk_q[ct * 16 + nn], qv);
        }
    }
    __syncthreads();
    {
        const int ch = threadIdx.x;
        const float v = (ch < CC) ? blk_s[ch] : blk_q[ch - CC];
        atomicAdd(&statsOut[(blockIdx.x & (NGRP - 1)) * 256 + ch], v);
    }
}

// ---------------------------------------------------------------------------
// Final BN + ReLU with in-kernel stats reduce; bf16 in, fp32 out.
// ---------------------------------------------------------------------------
__global__ __launch_bounds__(256) void bn_final(const ushort_t* __restrict__ Y,
                                                const float* __restrict__ statsIn,
                                                const float* __restrict__ g,
                                                const float* __restrict__ be,
                                                float* __restrict__ out) {
    __shared__ float sc_l[CC], sh_l[CC];
    if (threadIdx.x < CC) {
        const int c = threadIdx.x;
        float s = 0.f, q = 0.f;
#pragma unroll
        for (int gr = 0; gr < NGRP; ++gr) {
            s += statsIn[gr * 256 + c];
            q += statsIn[gr * 256 + CC + c];
        }
        const float m = s * (1.f / (float)NQ);
        const float v = fmaf(-m, m, q * (1.f / (float)NQ));
        const float rstd = rsqrtf(v + EPS_BN);
        const float scl = g[c] * rstd;
        sc_l[c] = scl;
        sh_l[c] = fmaf(-m, scl, be[c]);
    }
    __syncthreads();
    const int base = blockIdx.x * 1024 + threadIdx.x;   // 8-col group index
#pragma unroll
    for (int it = 0; it < 4; ++it) {
        const int i8 = base + it * 256;
        const int c8 = (i8 & 15) * 8;
        const uint4 u = *(const uint4*)&Y[(size_t)i8 * 8];
        const float4 s0 = *(const float4*)&sc_l[c8];
        const float4 s1 = *(const float4*)&sc_l[c8 + 4];
        const float4 h0 = *(const float4*)&sh_l[c8];
        const float4 h1 = *(const float4*)&sh_l[c8 + 4];
        float4 o0, o1;
        o0.x = fmaxf(fmaf(bflo(u.x), s0.x, h0.x), 0.f);
        o0.y = fmaxf(fmaf(bfhi(u.x), s0.y, h0.y), 0.f);
        o0.z = fmaxf(fmaf(bflo(u.y), s0.z, h0.z), 0.f);
        o0.w = fmaxf(fmaf(bfhi(u.y), s0.w, h0.w), 0.f);
        o1.x = fmaxf(fmaf(bflo(u.z), s1.x, h1.x), 0.f);
        o1.y = fmaxf(fmaf(bfhi(u.z), s1.y, h1.y), 0.f);
        o1.z = fmaxf(fmaf(bflo(u.w), s1.z, h1.z), 0.f);
        o1.w = fmaxf(fmaf(bfhi(u.w), s1.w, h1.w), 0.f);
        ((float4*)out)[i8 * 2 + 0] = o0;
        ((float4*)out)[i8 * 2 + 1] = o1;
    }
}

// ---------------------------------------------------------------------------
extern "C" void kernel_launch(void* const* d_in, const int* in_sizes, int n_in,
                              void* d_out, int out_size, void* d_ws, size_t ws_size,
                              hipStream_t stream) {
    (void)in_sizes; (void)n_in; (void)out_size; (void)ws_size;

    const float* pos1  = (const float*)d_in[0];
    const float* pos2  = (const float*)d_in[1];
    const float* feat2 = (const float*)d_in[2];
    const float* Wl[3]  = {(const float*)d_in[3], (const float*)d_in[7],  (const float*)d_in[11]};
    const float* bl[3]  = {(const float*)d_in[4], (const float*)d_in[8],  (const float*)d_in[12]};
    const float* gl[3]  = {(const float*)d_in[5], (const float*)d_in[9],  (const float*)d_in[13]};
    const float* bel[3] = {(const float*)d_in[6], (const float*)d_in[10], (const float*)d_in[14]};

    // Workspace layout (16B-aligned regions)
    char* ws = (char*)d_ws;
    ushort_t* B0 = (ushort_t*)ws;                          ws += (size_t)NQ * CC * 2;   // 8 MB
    ushort_t* B1 = (ushort_t*)ws;                          ws += (size_t)NQ * CC * 2;   // 8 MB
    float4* pts  = (float4*)ws;                            ws += (size_t)MC * 16;       // 128 KB
    int*   idx3  = (int*)ws;                               ws += (size_t)NQ * 3 * 4;
    float* w3    = (float*)ws;                             ws += (size_t)NQ * 3 * 4;
    float* stats = (float*)ws;                             ws += 3 * NGRP * 256 * 4;    // 24 KB
    int*   cnt   = (int*)ws;                               ws += (size_t)GT * 4;        // 1 MB
    int*   off   = (int*)ws;                               ws += (size_t)(GT + 4) * 4;
    int*   cursor= (int*)ws;                               ws += (size_t)GT * 4;
    int*   cellOf= (int*)ws;                               ws += (size_t)MC * 4;
    int*   blockSum = (int*)ws;                            ws += 256 * 4;
    ushort_t* Wbf = (ushort_t*)ws;                         // 96 KB

    // 0: zero stats + cnt (contiguous)
    hipMemsetAsync(stats, 0, (3 * NGRP * 256 + GT) * sizeof(float), stream);
    // 1: histogram + cellOf + W bf16 conversion
    prep_kernel<<<40, 256, 0, stream>>>(pos2, cnt, cellOf, Wl[0], Wl[1], Wl[2], Wbf);
    // 2-3: two-phase exclusive scan -> off, cursor
    scanA<<<256, 1024, 0, stream>>>(cnt, off, blockSum);
    scanC<<<256, 1024, 0, stream>>>(blockSum, off, cursor);
    // 4: scatter points into cell buckets
    scatter_kernel<<<32, 256, 0, stream>>>(pos2, cellOf, cursor, pts);
    // 5: grid KNN -> idx3, w3
    knn_query<<<NQ / 64, 256, 0, stream>>>(pos1, pts, off, pos2, idx3, w3);
    // 6: layer 0 (interp fused) -> B0 (bf16), st0
    float* st0 = stats + 0 * NGRP * 256;
    float* st1 = stats + 1 * NGRP * 256;
    float* st2 = stats + 2 * NGRP * 256;
    gemm_mfma<0><<<GEMM_B, 256, 0, stream>>>(feat2, idx3, w3,
                                             nullptr, nullptr, nullptr,
                                             Wbf + 0 * CC * CC, bl[0], B0, st0);
    // 7: layer 1 (stats-reduce + BN fused) -> B1, st1
    gemm_mfma<1><<<GEMM_B, 256, 0, stream>>>(B0, nullptr, nullptr,
                                             st0, gl[0], bel[0],
                                             Wbf + 1 * CC * CC, bl[1], B1, st1);
    // 8: layer 2 -> B0, st2
    gemm_mfma<1><<<GEMM_B, 256, 0, stream>>>(B1, nullptr, nullptr,
                                             st1, gl[1], bel[1],
                                             Wbf + 2 * CC * CC, bl[2], B0, st2);
    // 9: final BN+ReLU -> out (fp32)
    bn_final<<<GEMM_B, 256, 0, stream>>>(B0, st2, gl[2], bel[2], (float*)d_out);
}